// Round 22
// baseline (105.924 us; speedup 1.0000x reference)
//
#include <hip/hip_runtime.h>
#include <math.h>

constexpr int NQ      = 14;
constexpr int NSTATE  = 1 << 14;    // 16384
constexpr int NPARAMS = 140;
constexpr int BATCH   = 128;
constexpr int THREADS = 1024;

struct cplx { float re, im; };
__device__ __forceinline__ cplx cmul(cplx a, cplx b) {
    return { a.re*b.re - a.im*b.im, a.re*b.im + a.im*b.re };
}

// float -> bf16 bits, round-to-nearest-even
__device__ __forceinline__ unsigned int f2bf(float f) {
    union { float f; unsigned int u; } v; v.f = f;
    return (v.u + 0x7FFFu + ((v.u >> 16) & 1u)) >> 16;
}

__global__ __launch_bounds__(THREADS)
void qsim_kernel(const float* __restrict__ params,
                 unsigned int* __restrict__ out_u32) {
    __shared__ float2 st[NSTATE];      // 128 KiB
    __shared__ float2 gcs[NPARAMS];    // (cos, sin) of half-angles

    const int b   = blockIdx.x;
    const int tid = threadIdx.x;
    const float* P = params + b * NPARAMS;

    if (tid < NPARAMS) {
        float s, c;
        sincosf(0.5f * P[tid], &s, &c);
        gcs[tid] = make_float2(c, s);
    }
    for (int k = tid; k < NSTATE; k += THREADS)
        st[k] = make_float2(k == 0 ? 1.f : 0.f, 0.f);
    __syncthreads();

    int idx = 0;
    for (int layer = 0; layer < 2; ++layer) {
        // ---- fused 1-qubit rotations: U = Rz * Ry * Rx on qubit q ----
        for (int q = 0; q < NQ; ++q) {
            const float cx = gcs[idx].x,     sx = gcs[idx].y;
            const float cy = gcs[idx + 1].x, sy = gcs[idx + 1].y;
            const float cz = gcs[idx + 2].x, sz = gcs[idx + 2].y;
            // M = Ry * Rx ; U = Rz * M,  Rz = diag(cz - i sz, cz + i sz)
            cplx m00{ cy*cx,  sy*sx }, m01{ -sy*cx, -cy*sx };
            cplx m10{ sy*cx, -cy*sx }, m11{  cy*cx, -sy*sx };
            cplx z0{ cz, -sz }, z1{ cz, sz };
            cplx u00 = cmul(z0, m00), u01 = cmul(z0, m01);
            cplx u10 = cmul(z1, m10), u11 = cmul(z1, m11);

            const int p  = NQ - 1 - q;      // qubit 0 = MSB
            const int pm = (1 << p) - 1;
            for (int k = tid; k < NSTATE / 2; k += THREADS) {
                const int i0 = ((k & ~pm) << 1) | (k & pm);
                const int i1 = i0 | (1 << p);
                const float2 a0 = st[i0];
                const float2 a1 = st[i1];
                float2 b0, b1;
                b0.x = u00.re*a0.x - u00.im*a0.y + u01.re*a1.x - u01.im*a1.y;
                b0.y = u00.re*a0.y + u00.im*a0.x + u01.re*a1.y + u01.im*a1.x;
                b1.x = u10.re*a0.x - u10.im*a0.y + u11.re*a1.x - u11.im*a1.y;
                b1.y = u10.re*a0.y + u10.im*a0.x + u11.re*a1.y + u11.im*a1.x;
                st[i0] = b0;
                st[i1] = b1;
            }
            idx += 3;
            __syncthreads();
        }
        // ---- CRX rings: ascending (t=i+1), then descending (t=i-1) ----
        for (int ring = 0; ring < 2; ++ring) {
            for (int j = 0; j < NQ; ++j) {
                const int i = (ring == 0) ? j : (NQ - 1 - j);
                const int t = (ring == 0) ? ((i + 1) % NQ) : ((i + NQ - 1) % NQ);
                const float cr = gcs[idx].x, sr = gcs[idx].y;
                const int pc = NQ - 1 - i;
                const int pt = NQ - 1 - t;
                const int hi = pc > pt ? pc : pt;
                const int lo = pc > pt ? pt : pc;
                const int lm = (1 << lo) - 1;
                const int hm = (1 << hi) - 1;
                for (int k = tid; k < NSTATE / 4; k += THREADS) {
                    int x = ((k & ~lm) << 1) | (k & lm);
                    x     = ((x & ~hm) << 1) | (x & hm);
                    const int i0 = x | (1 << pc);
                    const int i1 = i0 | (1 << pt);
                    const float2 a0 = st[i0];
                    const float2 a1 = st[i1];
                    st[i0] = make_float2(cr*a0.x + sr*a1.y, cr*a0.y - sr*a1.x);
                    st[i1] = make_float2(cr*a1.x + sr*a0.y, cr*a1.y - sr*a0.x);
                }
                idx += 1;
                __syncthreads();
            }
        }
    }

    // ---- epilogue: IMAG-FIRST interleaved bf16: slot 2k = Im, 2k+1 = Re ----
    uint4* ob = (uint4*)(out_u32 + (size_t)b * NSTATE);
    for (int k = tid; k < NSTATE / 4; k += THREADS) {
        float2 a0 = st[4*k], a1 = st[4*k+1], a2 = st[4*k+2], a3 = st[4*k+3];
        uint4 w;
        w.x = f2bf(a0.y) | (f2bf(a0.x) << 16);
        w.y = f2bf(a1.y) | (f2bf(a1.x) << 16);
        w.z = f2bf(a2.y) | (f2bf(a2.x) << 16);
        w.w = f2bf(a3.y) | (f2bf(a3.x) << 16);
        ob[k] = w;
    }
}

extern "C" void kernel_launch(void* const* d_in, const int* in_sizes, int n_in,
                              void* d_out, int out_size, void* d_ws, size_t ws_size,
                              hipStream_t stream) {
    const float* params = (const float*)d_in[0];
    unsigned int* out = (unsigned int*)d_out;
    qsim_kernel<<<BATCH, THREADS, 0, stream>>>(params, out);
}